// Round 14
// baseline (2825.902 us; speedup 1.0000x reference)
//
#include <hip/hip_runtime.h>

typedef __attribute__((ext_vector_type(4))) float  f32x4;
typedef __attribute__((ext_vector_type(8))) short  short8;
typedef __attribute__((ext_vector_type(4))) short  short4v;
typedef __attribute__((ext_vector_type(4))) int    int4v;

__device__ __forceinline__ float bf2f(short s){
  unsigned u = ((unsigned)(unsigned short)s) << 16;
  float f; __builtin_memcpy(&f, &u, 4); return f;
}
__device__ __forceinline__ short f2bf(float x){
  unsigned u; __builtin_memcpy(&u, &x, 4);
  u = (u + 0x7fffu + ((u >> 16) & 1u)) >> 16;
  return (short)u;
}
__device__ __forceinline__ float sigm(float x){ return 1.f / (1.f + __expf(-x)); }
__device__ __forceinline__ float ftanh(float x){ return 1.f - 2.f / (__expf(2.f * x) + 1.f); }

// ---- IC-coherent (sc1) pipelined vector ops: issue many, wait once ----
__device__ __forceinline__ short8 ld_b128_sc1(const short* p){
  short8 r;
  asm volatile("global_load_dwordx4 %0, %1, off sc1" : "=&v"(r) : "v"(p) : "memory");
  return r;
}
__device__ __forceinline__ int4v ld_i4_sc1(const int* p){
  int4v r;
  asm volatile("global_load_dwordx4 %0, %1, off sc1" : "=&v"(r) : "v"(p) : "memory");
  return r;
}
__device__ __forceinline__ void st_b128i_sc1(short* p, int4v v){
  asm volatile("global_store_dwordx4 %0, %1, off sc1" :: "v"(p), "v"(v) : "memory");
}
__device__ __forceinline__ void st_dword_sc1(int* p, int v){
  asm volatile("global_store_dword %0, %1, off sc1" :: "v"(p), "v"(v) : "memory");
}
__device__ __forceinline__ void wait_vm0(){
  asm volatile("s_waitcnt vmcnt(0)" ::: "memory");
  __builtin_amdgcn_sched_barrier(0);
}

// ---------------------------------------------------------------------------
// Generic bf16-MFMA GEMM: C[M,N] = A[M,K] * B[K,N] + bias[N]
// ---------------------------------------------------------------------------
template<int AF32, int OF32>
__global__ __launch_bounds__(256) void gemm_bias(const void* __restrict__ Av,
                                                 const float* __restrict__ B,
                                                 const float* __restrict__ bias,
                                                 void* __restrict__ Cv,
                                                 int M, int N, int K)
{
  __shared__ __align__(16) short As[128 * 40];
  __shared__ __align__(16) short Bs[128 * 40];
  int tid  = threadIdx.x;
  int col0 = blockIdx.x * 128, row0 = blockIdx.y * 128;
  int lane = tid & 63, wave = tid >> 6;
  int wm = (wave >> 1) * 64, wn = (wave & 1) * 64;

  f32x4 acc[4][4];
  for (int mi = 0; mi < 4; mi++)
    for (int ni = 0; ni < 4; ni++)
      for (int q = 0; q < 4; q++) acc[mi][ni][q] = 0.f;

  for (int kt = 0; kt < K; kt += 32) {
    __syncthreads();
    if (AF32) {
      const float* A = (const float*)Av;
      for (int i = 0; i < 4; i++) {
        int idx = tid + i * 256;
        int r = idx >> 3, c4 = (idx & 7) << 2;
        f32x4 v = *(const f32x4*)(A + (size_t)(row0 + r) * K + kt + c4);
        short4v o;
        for (int q = 0; q < 4; q++) o[q] = f2bf(v[q]);
        *(short4v*)&As[r * 40 + c4] = o;
      }
    } else {
      const short* A = (const short*)Av;
      for (int i = 0; i < 2; i++) {
        int idx = tid + i * 256;
        int r = idx >> 2, c8 = (idx & 3) << 3;
        short8 v = *(const short8*)(A + (size_t)(row0 + r) * K + kt + c8);
        *(short8*)&As[r * 40 + c8] = v;
      }
    }
    for (int i = 0; i < 4; i++) {
      int idx = tid + i * 256;
      int kr = idx >> 5, c4 = (idx & 31) << 2;
      f32x4 v = *(const f32x4*)(B + (size_t)(kt + kr) * N + col0 + c4);
      for (int e = 0; e < 4; e++) Bs[(c4 + e) * 40 + kr] = f2bf(v[e]);
    }
    __syncthreads();

    int fr = lane & 15, fo = (lane >> 4) << 3;
    short8 af[4], bfr[4];
    for (int mi = 0; mi < 4; mi++) af[mi]  = *(short8*)&As[(wm + mi * 16 + fr) * 40 + fo];
    for (int ni = 0; ni < 4; ni++) bfr[ni] = *(short8*)&Bs[(wn + ni * 16 + fr) * 40 + fo];
    for (int mi = 0; mi < 4; mi++)
      for (int ni = 0; ni < 4; ni++)
        acc[mi][ni] = __builtin_amdgcn_mfma_f32_16x16x32_bf16(af[mi], bfr[ni], acc[mi][ni], 0, 0, 0);
  }

  int efr = lane & 15, efrow = (lane >> 4) << 2;
  for (int ni = 0; ni < 4; ni++) {
    int col = col0 + wn + ni * 16 + efr;
    float bv = bias[col];
    for (int mi = 0; mi < 4; mi++) {
      for (int q = 0; q < 4; q++) {
        int row = row0 + wm + mi * 16 + efrow + q;
        float v = acc[mi][ni][q] + bv;
        if (OF32) ((float*)Cv)[(size_t)row * N + col] = v;
        else      ((short*)Cv)[(size_t)row * N + col] = f2bf(v);
      }
    }
  }
}

// ---------------------------------------------------------------------------
// ws = s @ atW + atW_b
// ---------------------------------------------------------------------------
__global__ __launch_bounds__(128) void att_ws_kernel(const float* __restrict__ s,
                                                     const float* __restrict__ atW,
                                                     const float* __restrict__ atWb,
                                                     float* __restrict__ ws)
{
  int b = blockIdx.x, a = threadIdx.x;
  float acc = atWb[a];
  for (int k = 0; k < 128; k++) acc += s[b * 128 + k] * atW[k * 128 + a];
  ws[b * 128 + a] = acc;
}

// ---------------------------------------------------------------------------
// Persistent bidirectional-LSTM scan (R10 topology + flag protocol, verified).
// R14 change: SWAPPED-OPERAND MFMA with weight columns ordered j*4+g:
//   A = Wh^T frag (regs), B = h^T frag (same b128 loads as R10).
//   D[row=rg*4+q][col=n] -> (j = j0 + nt*4 + rg, gate = q, batch = w*16+n):
//   all 4 gates of a cell land in ONE thread -> register-local epilogue.
//   The gl LDS transpose, its barrier, and its reads are GONE.
//   Output: 4-lane __shfl gather; rg==0 lanes store one b128 per batch row.
// Flag publish/poll is byte-identical to R10.
// ---------------------------------------------------------------------------
template<int H, int NB>
__device__ __forceinline__ void persistent_scan(
    const short* __restrict__ xg, const float* __restrict__ Wh,
    short* __restrict__ hall, int* __restrict__ flags,
    int wg, int dir)
{
  constexpr int C = 2 * H, H4 = 4 * H, KB = H / 32;
  const int tid = threadIdx.x, lane = tid & 63, w = tid >> 6;
  const int j0 = wg * 8, dircol = dir ? H : 0;
  const int n = lane & 15, rg = lane >> 4;
  const int batch = w * 16 + n;

  // A-frag weights (once): M-tile nt covers j_local = nt*4 + (row>>2), g = row&3.
  // Lane's A row = n: colG = (n&3)*H + j0 + nt*4 + (n>>2); k = kb*32 + rg*8 + e.
  short8 bw[2][KB];
#pragma unroll
  for (int nt = 0; nt < 2; nt++) {
    int colG = (n & 3) * H + j0 + nt * 4 + (n >> 2);
#pragma unroll
    for (int kb = 0; kb < KB; kb++)
#pragma unroll
      for (int e = 0; e < 8; e++)
        bw[nt][kb][e] = f2bf(Wh[(size_t)(kb * 32 + rg * 8 + e) * H4 + colG]);
  }

  float cst[2] = {0.f, 0.f};        // cells (batch, j0+rg) and (batch, j0+4+rg)

  // xg prefetch for step 0: xgr[nt][g] for this thread's two cells
  short xgr[2][4];
  {
    int t0 = dir ? 511 : 0;
#pragma unroll
    for (int nt = 0; nt < 2; nt++)
#pragma unroll
      for (int g = 0; g < 4; g++)
        xgr[nt][g] = xg[(size_t)(t0 * 64 + batch) * H4 + g * H + j0 + nt * 4 + rg];
  }

  for (int s = 0; s < 512; s++) {
    int t = dir ? 511 - s : s;
    f32x4 acc[2];
#pragma unroll
    for (int q = 0; q < 4; q++) { acc[0][q] = 0.f; acc[1][q] = 0.f; }

    if (s > 0) {
      int tprev = dir ? t + 1 : t - 1;
      const short* hb = hall + ((size_t)tprev * 64 + batch) * C + dircol;
      short8 hv[KB];
#pragma unroll
      for (int kb = 0; kb < KB; kb++)              // pipelined, ONE round-trip
        hv[kb] = ld_b128_sc1(hb + kb * 32 + rg * 8);
      wait_vm0();
#pragma unroll
      for (int kb = 0; kb < KB; kb++) {
        acc[0] = __builtin_amdgcn_mfma_f32_16x16x32_bf16(bw[0][kb], hv[kb], acc[0], 0, 0, 0);
        acc[1] = __builtin_amdgcn_mfma_f32_16x16x32_bf16(bw[1][kb], hv[kb], acc[1], 0, 0, 0);
      }
    }

    // register-local epilogue: acc[nt][q] = gate q of (batch, j0 + nt*4 + rg)
    unsigned hpk = 0;
#pragma unroll
    for (int nt = 0; nt < 2; nt++) {
      float a_ = acc[nt][0] + bf2f(xgr[nt][0]);
      float i_ = acc[nt][1] + bf2f(xgr[nt][1]);
      float f_ = acc[nt][2] + bf2f(xgr[nt][2]);
      float o_ = acc[nt][3] + bf2f(xgr[nt][3]);
      float cc = ftanh(a_) * sigm(i_) + cst[nt] * sigm(f_);
      cst[nt] = cc;
      unsigned hb16 = (unsigned short)f2bf(ftanh(cc) * sigm(o_));
      hpk |= hb16 << (16 * nt);
    }
    // gather 8 j's of this batch into the rg==0 lane: u_k from lane n+16k
    unsigned u0 = __shfl(hpk, n,      64);
    unsigned u1 = __shfl(hpk, n + 16, 64);
    unsigned u2 = __shfl(hpk, n + 32, 64);
    unsigned u3 = __shfl(hpk, n + 48, 64);
    if (rg == 0) {
      int4v dv;
      dv[0] = (int)((u0 & 0xffffu) | (u1 << 16));            // j0+0, j0+1
      dv[1] = (int)((u2 & 0xffffu) | (u3 << 16));            // j0+2, j0+3
      dv[2] = (int)((u0 >> 16) | (u1 & 0xffff0000u));        // j0+4, j0+5
      dv[3] = (int)((u2 >> 16) | (u3 & 0xffff0000u));        // j0+6, j0+7
      st_b128i_sc1(hall + ((size_t)t * 64 + batch) * C + dircol + j0, dv);
    }

    if (s < 511) {
      wait_vm0();           // own h stores ACKed at IC (per-wave)
      __syncthreads();      // => ALL waves' stores drained
      if (tid == 0) st_dword_sc1(flags + wg, s + 1);   // publish

      // prefetch next step's xg (overlaps the poll)
      int tn = dir ? t - 1 : t + 1;
#pragma unroll
      for (int nt = 0; nt < 2; nt++)
#pragma unroll
        for (int g = 0; g < 4; g++)
          xgr[nt][g] = xg[(size_t)(tn * 64 + batch) * H4 + g * H + j0 + nt * 4 + rg];

      if (tid == 0) {       // pipelined poll: NB/4 b128 loads, one wait
        for (;;) {
          int4v f[NB / 4];
#pragma unroll
          for (int i = 0; i < NB / 4; i++) f[i] = ld_i4_sc1(flags + i * 4);
          wait_vm0();
          int ok = 1;
#pragma unroll
          for (int i = 0; i < NB / 4; i++)
#pragma unroll
            for (int j = 0; j < 4; j++) ok &= (f[i][j] > s);
          if (ok) break;
          __builtin_amdgcn_s_sleep(1);
        }
      }
      __syncthreads();
    }
  }
}

__global__ __launch_bounds__(256) void lstm_persistent(
    const short* __restrict__ xgf0, const short* __restrict__ xgb0,
    const short* __restrict__ xgf1, const short* __restrict__ xgb1,
    const float* __restrict__ fh0, const float* __restrict__ bh0,
    const float* __restrict__ fh1, const float* __restrict__ bh1,
    short* __restrict__ hall0, short* __restrict__ hall1, int* __restrict__ bar)
{
  int bx = blockIdx.x;
  if (bx < 64) {
    int dir = bx >> 5, wg = bx & 31;
    persistent_scan<256, 32>(dir ? xgb0 : xgf0, dir ? bh0 : fh0, hall0,
                             bar + (dir ? 64 : 0), wg, dir);
  } else {
    int r = bx - 64, dir = r >> 4, wg = r & 15;
    persistent_scan<128, 16>(dir ? xgb1 : xgf1, dir ? bh1 : fh1, hall1,
                             bar + 128 + (dir ? 64 : 0), wg, dir);
  }
}

// ---------------------------------------------------------------------------
// logits[r] = tanh(vh[r,:] + ws[b,:]) . atw + atw_b
// ---------------------------------------------------------------------------
__global__ __launch_bounds__(256) void logits_kernel(const float* __restrict__ vh,
                                                     const float* __restrict__ ws,
                                                     const float* __restrict__ atw,
                                                     const float* __restrict__ atwb,
                                                     float* __restrict__ lg)
{
  int wid  = (int)((blockIdx.x * 256 + threadIdx.x) >> 6);
  int lane = threadIdx.x & 63;
  if (wid >= 32768) return;
  int b = wid & 63;
  float x0 = vh[(size_t)wid * 128 + lane]      + ws[b * 128 + lane];
  float x1 = vh[(size_t)wid * 128 + 64 + lane] + ws[b * 128 + 64 + lane];
  float v = ftanh(x0) * atw[lane] + ftanh(x1) * atw[64 + lane];
  for (int off = 32; off; off >>= 1) v += __shfl_down(v, off);
  if (lane == 0) lg[wid] = v + atwb[0];
}

// ---------------------------------------------------------------------------
// Per-batch softmax over T + context
// ---------------------------------------------------------------------------
__global__ __launch_bounds__(256) void softmax_ctx(const float* __restrict__ lg,
                                                   const short* __restrict__ hall,
                                                   float* __restrict__ ctx, int C)
{
  int b = blockIdx.x, tid = threadIdx.x, lane = tid & 63, wv = tid >> 6;
  __shared__ float ebuf[512];
  __shared__ float red[8];
  float l0 = lg[tid * 64 + b];
  float l1 = lg[(tid + 256) * 64 + b];
  float m = fmaxf(l0, l1);
  for (int o = 32; o; o >>= 1) m = fmaxf(m, __shfl_xor(m, o));
  if (lane == 0) red[wv] = m;
  __syncthreads();
  m = fmaxf(fmaxf(red[0], red[1]), fmaxf(red[2], red[3]));
  float e0 = __expf(l0 - m), e1 = __expf(l1 - m);
  ebuf[tid] = e0; ebuf[tid + 256] = e1;
  float sm = e0 + e1;
  for (int o = 32; o; o >>= 1) sm += __shfl_xor(sm, o);
  if (lane == 0) red[4 + wv] = sm;
  __syncthreads();
  sm = red[4] + red[5] + red[6] + red[7];
  float inv = 1.f / (sm * 512.f);
  for (int c = tid; c < C; c += 256) {
    float acc = 0.f;
    const short* hp = hall + (size_t)b * C + c;
    for (int t = 0; t < 512; t++) acc += ebuf[t] * bf2f(hp[(size_t)t * 64 * C]);
    ctx[b * C + c] = acc * inv;
  }
}

// ---------------------------------------------------------------------------
__global__ __launch_bounds__(256) void final_kernel(const float* __restrict__ ctx0,
                                                    const float* __restrict__ ctx1,
                                                    const float* __restrict__ w0,
                                                    const float* __restrict__ b0,
                                                    const float* __restrict__ w1,
                                                    const float* __restrict__ b1,
                                                    float* __restrict__ out)
{
  int b = blockIdx.x, o = threadIdx.x;
  float acc = b0[o] + b1[o];
  for (int c = 0; c < 512; c++) acc += ctx0[b * 512 + c] * w0[c * 256 + o];
  for (int c = 0; c < 256; c++) acc += ctx1[b * 256 + c] * w1[c * 256 + o];
  out[b * 256 + o] = ftanh(acc);
}

// ---------------------------------------------------------------------------
extern "C" void kernel_launch(void* const* d_in, const int* in_sizes, int n_in,
                              void* d_out, int out_size, void* d_ws, size_t ws_size,
                              hipStream_t stream)
{
  const float* x0    = (const float*)d_in[0];
  const float* x1    = (const float*)d_in[1];
  const float* sIn   = (const float*)d_in[2];
  const float* emb_w0 = (const float*)d_in[3];  const float* emb_b0 = (const float*)d_in[4];
  const float* fx_w0  = (const float*)d_in[5];  const float* fx_b0  = (const float*)d_in[6];
  const float* fh_w0  = (const float*)d_in[7];
  const float* bx_w0  = (const float*)d_in[8];  const float* bx_b0  = (const float*)d_in[9];
  const float* bh_w0  = (const float*)d_in[10];
  const float* atV_w0 = (const float*)d_in[11]; const float* atV_b0 = (const float*)d_in[12];
  const float* atW_w0 = (const float*)d_in[13]; const float* atW_b0 = (const float*)d_in[14];
  const float* atw_w0 = (const float*)d_in[15]; const float* atw_b0 = (const float*)d_in[16];
  const float* lgd_w0 = (const float*)d_in[17]; const float* lgd_b0 = (const float*)d_in[18];
  const float* emb_w1 = (const float*)d_in[19]; const float* emb_b1 = (const float*)d_in[20];
  const float* fx_w1  = (const float*)d_in[21]; const float* fx_b1  = (const float*)d_in[22];
  const float* fh_w1  = (const float*)d_in[23];
  const float* bx_w1  = (const float*)d_in[24]; const float* bx_b1  = (const float*)d_in[25];
  const float* bh_w1  = (const float*)d_in[26];
  const float* atV_w1 = (const float*)d_in[27]; const float* atV_b1 = (const float*)d_in[28];
  const float* atW_w1 = (const float*)d_in[29]; const float* atW_b1 = (const float*)d_in[30];
  const float* atw_w1 = (const float*)d_in[31]; const float* atw_b1 = (const float*)d_in[32];
  const float* lgd_w1 = (const float*)d_in[33]; const float* lgd_b1 = (const float*)d_in[34];
  float* out = (float*)d_out;

  char* wp = (char*)d_ws;
  auto alloc = [&](size_t bytes) -> void* {
    void* p = wp; wp += (bytes + 255) & ~(size_t)255; return p;
  };
  int*   bar   = (int*)alloc(1024);                 // flags: m0d0@0, m0d1@64, m1d0@128, m1d1@192
  short* h0_0  = (short*)alloc(32768ull * 512 * 2);
  short* h0_1  = (short*)alloc(32768ull * 128 * 2);
  short* xgf0  = (short*)alloc(32768ull * 1024 * 2);
  short* xgb0  = (short*)alloc(32768ull * 1024 * 2);
  short* xgf1  = (short*)alloc(32768ull * 512 * 2);
  short* xgb1  = (short*)alloc(32768ull * 512 * 2);
  short* hall0 = (short*)alloc(32768ull * 512 * 2);
  short* hall1 = (short*)alloc(32768ull * 256 * 2);
  float* vh0   = (float*)alloc(32768ull * 128 * 4);
  float* vh1   = (float*)alloc(32768ull * 128 * 4);
  float* wsb0  = (float*)alloc(64 * 128 * 4);
  float* wsb1  = (float*)alloc(64 * 128 * 4);
  float* lg0   = (float*)alloc(32768 * 4);
  float* lg1   = (float*)alloc(32768 * 4);
  float* ctx0  = (float*)alloc(64 * 512 * 4);
  float* ctx1  = (float*)alloc(64 * 256 * 4);

  // embeddings (f32 in, bf16 out)
  gemm_bias<1, 0><<<dim3(4, 256), 256, 0, stream>>>(x0, emb_w0, emb_b0, h0_0, 32768, 512, 2048);
  gemm_bias<1, 0><<<dim3(1, 256), 256, 0, stream>>>(x1, emb_w1, emb_b1, h0_1, 32768, 128, 128);
  // input projections (bf16 in, bf16 out)
  gemm_bias<0, 0><<<dim3(8, 256), 256, 0, stream>>>(h0_0, fx_w0, fx_b0, xgf0, 32768, 1024, 512);
  gemm_bias<0, 0><<<dim3(8, 256), 256, 0, stream>>>(h0_0, bx_w0, bx_b0, xgb0, 32768, 1024, 512);
  gemm_bias<0, 0><<<dim3(4, 256), 256, 0, stream>>>(h0_1, fx_w1, fx_b1, xgf1, 32768, 512, 128);
  gemm_bias<0, 0><<<dim3(4, 256), 256, 0, stream>>>(h0_1, bx_w1, bx_b1, xgb1, 32768, 512, 128);
  // attention s-projection
  att_ws_kernel<<<64, 128, 0, stream>>>(sIn, atW_w0, atW_b0, wsb0);
  att_ws_kernel<<<64, 128, 0, stream>>>(sIn, atW_w1, atW_b1, wsb1);

  // persistent bidirectional LSTM scans (one dispatch, 512 internal steps)
  hipMemsetAsync(bar, 0, 1024, stream);
  lstm_persistent<<<96, 256, 0, stream>>>(xgf0, xgb0, xgf1, xgb1,
                                          fh_w0, bh_w0, fh_w1, bh_w1,
                                          hall0, hall1, bar);

  // attention
  gemm_bias<0, 1><<<dim3(1, 256), 256, 0, stream>>>(hall0, atV_w0, atV_b0, vh0, 32768, 128, 512);
  gemm_bias<0, 1><<<dim3(1, 256), 256, 0, stream>>>(hall1, atV_w1, atV_b1, vh1, 32768, 128, 256);
  logits_kernel<<<8192, 256, 0, stream>>>(vh0, wsb0, atw_w0, atw_b0, lg0);
  logits_kernel<<<8192, 256, 0, stream>>>(vh1, wsb1, atw_w1, atw_b1, lg1);
  softmax_ctx<<<64, 256, 0, stream>>>(lg0, hall0, ctx0, 512);
  softmax_ctx<<<64, 256, 0, stream>>>(lg1, hall1, ctx1, 256);
  final_kernel<<<64, 256, 0, stream>>>(ctx0, ctx1, lgd_w0, lgd_b0, lgd_w1, lgd_b1, out);
}

// Round 15
// 2410.472 us; speedup vs baseline: 1.1723x; 1.1723x over previous
//
#include <hip/hip_runtime.h>

typedef __attribute__((ext_vector_type(4))) float  f32x4;
typedef __attribute__((ext_vector_type(8))) short  short8;
typedef __attribute__((ext_vector_type(4))) short  short4v;
typedef __attribute__((ext_vector_type(4))) int    int4v;

__device__ __forceinline__ float bf2f(short s){
  unsigned u = ((unsigned)(unsigned short)s) << 16;
  float f; __builtin_memcpy(&f, &u, 4); return f;
}
__device__ __forceinline__ short f2bf(float x){
  unsigned u; __builtin_memcpy(&u, &x, 4);
  u = (u + 0x7fffu + ((u >> 16) & 1u)) >> 16;
  return (short)u;
}
__device__ __forceinline__ float sigm(float x){ return 1.f / (1.f + __expf(-x)); }
__device__ __forceinline__ float ftanh(float x){ return 1.f - 2.f / (__expf(2.f * x) + 1.f); }

// ---- IC-coherent (sc1) pipelined vector ops: issue many, wait once ----
__device__ __forceinline__ short8 ld_b128_sc1(const short* p){
  short8 r;
  asm volatile("global_load_dwordx4 %0, %1, off sc1" : "=&v"(r) : "v"(p) : "memory");
  return r;
}
__device__ __forceinline__ int4v ld_i4_sc1(const int* p){
  int4v r;
  asm volatile("global_load_dwordx4 %0, %1, off sc1" : "=&v"(r) : "v"(p) : "memory");
  return r;
}
__device__ __forceinline__ void st_dword_sc1(int* p, int v){
  asm volatile("global_store_dword %0, %1, off sc1" :: "v"(p), "v"(v) : "memory");
}
__device__ __forceinline__ void wait_vm0(){
  asm volatile("s_waitcnt vmcnt(0)" ::: "memory");
  __builtin_amdgcn_sched_barrier(0);
}

// ---------------------------------------------------------------------------
// Weight preprocessing: Wt[n][k] = bf16(W[k][n])  (LDS-tiled transpose+cvt)
// ---------------------------------------------------------------------------
__global__ __launch_bounds__(256) void transpose_cvt(const float* __restrict__ W,
                                                     short* __restrict__ Wt,
                                                     int K, int N)
{
  __shared__ float tile[32][33];
  int kt = blockIdx.x * 32, nt = blockIdx.y * 32;
  int tx = threadIdx.x & 31, ty = threadIdx.x >> 5;   // 32 x 8
#pragma unroll
  for (int i = 0; i < 4; i++) {
    int k = kt + ty + i * 8, n = nt + tx;
    if (k < K && n < N) tile[ty + i * 8][tx] = W[(size_t)k * N + n];
  }
  __syncthreads();
#pragma unroll
  for (int i = 0; i < 4; i++) {
    int n = nt + ty + i * 8, k = kt + tx;
    if (n < N && k < K) Wt[(size_t)n * K + k] = f2bf(tile[tx][ty + i * 8]);
  }
}

// ---------------------------------------------------------------------------
// bf16-MFMA GEMM with PRE-TRANSPOSED bf16 B: C[M,N] = A[M,K] * Bt[N,K]^T + bias
// A is f32 (AF32=1, converted in staging) or bf16 (AF32=0). B staging is now
// two short8 loads + two b128 LDS stores (no f32 loads, no cvt VALU).
// ---------------------------------------------------------------------------
template<int AF32, int OF32>
__global__ __launch_bounds__(256) void gemm_bias(const void* __restrict__ Av,
                                                 const short* __restrict__ Bt,
                                                 const float* __restrict__ bias,
                                                 void* __restrict__ Cv,
                                                 int M, int N, int K)
{
  __shared__ __align__(16) short As[128 * 40];
  __shared__ __align__(16) short Bs[128 * 40];
  int tid  = threadIdx.x;
  int col0 = blockIdx.x * 128, row0 = blockIdx.y * 128;
  int lane = tid & 63, wave = tid >> 6;
  int wm = (wave >> 1) * 64, wn = (wave & 1) * 64;

  f32x4 acc[4][4];
  for (int mi = 0; mi < 4; mi++)
    for (int ni = 0; ni < 4; ni++)
      for (int q = 0; q < 4; q++) acc[mi][ni][q] = 0.f;

  for (int kt = 0; kt < K; kt += 32) {
    __syncthreads();
    if (AF32) {
      const float* A = (const float*)Av;
      for (int i = 0; i < 4; i++) {
        int idx = tid + i * 256;
        int r = idx >> 3, c4 = (idx & 7) << 2;
        f32x4 v = *(const f32x4*)(A + (size_t)(row0 + r) * K + kt + c4);
        short4v o;
        for (int q = 0; q < 4; q++) o[q] = f2bf(v[q]);
        *(short4v*)&As[r * 40 + c4] = o;
      }
    } else {
      const short* A = (const short*)Av;
      for (int i = 0; i < 2; i++) {
        int idx = tid + i * 256;
        int r = idx >> 2, c8 = (idx & 3) << 3;
        short8 v = *(const short8*)(A + (size_t)(row0 + r) * K + kt + c8);
        *(short8*)&As[r * 40 + c8] = v;
      }
    }
    // B tile: rows of Bt (bf16, pre-transposed) — lean vector staging
    for (int i = 0; i < 2; i++) {
      int idx = tid + i * 256;
      int r = idx >> 2, c8 = (idx & 3) << 3;
      short8 v = *(const short8*)(Bt + (size_t)(col0 + r) * K + kt + c8);
      *(short8*)&Bs[r * 40 + c8] = v;
    }
    __syncthreads();

    int fr = lane & 15, fo = (lane >> 4) << 3;
    short8 af[4], bfr[4];
    for (int mi = 0; mi < 4; mi++) af[mi]  = *(short8*)&As[(wm + mi * 16 + fr) * 40 + fo];
    for (int ni = 0; ni < 4; ni++) bfr[ni] = *(short8*)&Bs[(wn + ni * 16 + fr) * 40 + fo];
    for (int mi = 0; mi < 4; mi++)
      for (int ni = 0; ni < 4; ni++)
        acc[mi][ni] = __builtin_amdgcn_mfma_f32_16x16x32_bf16(af[mi], bfr[ni], acc[mi][ni], 0, 0, 0);
  }

  int efr = lane & 15, efrow = (lane >> 4) << 2;
  for (int ni = 0; ni < 4; ni++) {
    int col = col0 + wn + ni * 16 + efr;
    float bv = bias[col];
    for (int mi = 0; mi < 4; mi++) {
      for (int q = 0; q < 4; q++) {
        int row = row0 + wm + mi * 16 + efrow + q;
        float v = acc[mi][ni][q] + bv;
        if (OF32) ((float*)Cv)[(size_t)row * N + col] = v;
        else      ((short*)Cv)[(size_t)row * N + col] = f2bf(v);
      }
    }
  }
}

// ---------------------------------------------------------------------------
// ws = s @ atW + atW_b
// ---------------------------------------------------------------------------
__global__ __launch_bounds__(128) void att_ws_kernel(const float* __restrict__ s,
                                                     const float* __restrict__ atW,
                                                     const float* __restrict__ atWb,
                                                     float* __restrict__ ws)
{
  int b = blockIdx.x, a = threadIdx.x;
  float acc = atWb[a];
  for (int k = 0; k < 128; k++) acc += s[b * 128 + k] * atW[k * 128 + a];
  ws[b * 128 + a] = acc;
}

// ---------------------------------------------------------------------------
// Persistent bidirectional-LSTM scan — R10 structure, verified @1757us:
//   (a) h_prev loads: pipelined b128 sc1 loads, ONE vmcnt wait, then MFMAs
//   (b) step barrier: per-block flag store + tid0 pipelined flag poll
// ---------------------------------------------------------------------------
template<int H, int NB>
__device__ __forceinline__ void persistent_scan(
    const short* __restrict__ xg, const float* __restrict__ Wh,
    short* __restrict__ hall, int* __restrict__ flags,
    int wg, int dir, float* gl)
{
  constexpr int C = 2 * H, H4 = 4 * H, KB = H / 32;
  int tid = threadIdx.x, lane = tid & 63, w = tid >> 6;
  int j0 = wg * 8, dircol = dir ? H : 0;
  int n = lane & 15, ko = (lane >> 4) << 3;

  short8 bw[2][KB];
#pragma unroll
  for (int nt = 0; nt < 2; nt++) {
    int col = (n >> 2) * H + j0 + nt * 4 + (n & 3);
#pragma unroll
    for (int kb = 0; kb < KB; kb++)
#pragma unroll
      for (int e = 0; e < 8; e++)
        bw[nt][kb][e] = f2bf(Wh[(size_t)(kb * 32 + ko + e) * H4 + col]);
  }

  int batch0 = w * 16 + ((lane >> 4) << 2);
  int rowA   = w * 16 + n;
  int eb = tid >> 2, ejp = tid & 3;
  float c0 = 0.f, c1 = 0.f;

  int t = dir ? 511 : 0;
  short xgr[2][4];
#pragma unroll
  for (int nt = 0; nt < 2; nt++) {
    int col = (n >> 2) * H + j0 + nt * 4 + (n & 3);
#pragma unroll
    for (int q = 0; q < 4; q++)
      xgr[nt][q] = xg[(size_t)(t * 64 + batch0 + q) * H4 + col];
  }

  for (int s = 0; s < 512; s++) {
    t = dir ? 511 - s : s;
    f32x4 acc[2];
#pragma unroll
    for (int q = 0; q < 4; q++) { acc[0][q] = 0.f; acc[1][q] = 0.f; }

    if (s > 0) {
      int tprev = dir ? t + 1 : t - 1;
      const short* hb = hall + ((size_t)tprev * 64 + rowA) * C + dircol;
      short8 hv[KB];
#pragma unroll
      for (int kb = 0; kb < KB; kb++)
        hv[kb] = ld_b128_sc1(hb + kb * 32 + ko);
      wait_vm0();
#pragma unroll
      for (int kb = 0; kb < KB; kb++) {
        acc[0] = __builtin_amdgcn_mfma_f32_16x16x32_bf16(hv[kb], bw[0][kb], acc[0], 0, 0, 0);
        acc[1] = __builtin_amdgcn_mfma_f32_16x16x32_bf16(hv[kb], bw[1][kb], acc[1], 0, 0, 0);
      }
    }

#pragma unroll
    for (int nt = 0; nt < 2; nt++) {
      int gcol = (n >> 2) * 8 + nt * 4 + (n & 3);
#pragma unroll
      for (int q = 0; q < 4; q++)
        gl[(batch0 + q) * 33 + gcol] = acc[nt][q] + bf2f(xgr[nt][q]);
    }
    __syncthreads();

    {
      const float* gb = gl + eb * 33 + ejp * 2;
      float a0 = gb[0],  a1 = gb[1];
      float i0 = gb[8],  i1 = gb[9];
      float f0 = gb[16], f1 = gb[17];
      float o0 = gb[24], o1 = gb[25];
      c0 = ftanh(a0) * sigm(i0) + c0 * sigm(f0);
      c1 = ftanh(a1) * sigm(i1) + c1 * sigm(f1);
      unsigned h0 = (unsigned short)f2bf(ftanh(c0) * sigm(o0));
      unsigned h1 = (unsigned short)f2bf(ftanh(c1) * sigm(o1));
      st_dword_sc1((int*)(hall + ((size_t)t * 64 + eb) * C + dircol + j0 + ejp * 2),
                   (int)(h0 | (h1 << 16)));
    }

    if (s < 511) {
      wait_vm0();
      __syncthreads();
      if (tid == 0) st_dword_sc1(flags + wg, s + 1);

      int tn = dir ? t - 1 : t + 1;
#pragma unroll
      for (int nt = 0; nt < 2; nt++) {
        int col = (n >> 2) * H + j0 + nt * 4 + (n & 3);
#pragma unroll
        for (int q = 0; q < 4; q++)
          xgr[nt][q] = xg[(size_t)(tn * 64 + batch0 + q) * H4 + col];
      }

      if (tid == 0) {
        for (;;) {
          int4v f[NB / 4];
#pragma unroll
          for (int i = 0; i < NB / 4; i++) f[i] = ld_i4_sc1(flags + i * 4);
          wait_vm0();
          int ok = 1;
#pragma unroll
          for (int i = 0; i < NB / 4; i++)
#pragma unroll
            for (int j = 0; j < 4; j++) ok &= (f[i][j] > s);
          if (ok) break;
          __builtin_amdgcn_s_sleep(1);
        }
      }
      __syncthreads();
    }
  }
}

__global__ __launch_bounds__(256) void lstm_persistent(
    const short* __restrict__ xgf0, const short* __restrict__ xgb0,
    const short* __restrict__ xgf1, const short* __restrict__ xgb1,
    const float* __restrict__ fh0, const float* __restrict__ bh0,
    const float* __restrict__ fh1, const float* __restrict__ bh1,
    short* __restrict__ hall0, short* __restrict__ hall1, int* __restrict__ bar)
{
  __shared__ float gl[64 * 33];
  int bx = blockIdx.x;
  if (bx < 64) {
    int dir = bx >> 5, wg = bx & 31;
    persistent_scan<256, 32>(dir ? xgb0 : xgf0, dir ? bh0 : fh0, hall0,
                             bar + (dir ? 64 : 0), wg, dir, gl);
  } else {
    int r = bx - 64, dir = r >> 4, wg = r & 15;
    persistent_scan<128, 16>(dir ? xgb1 : xgf1, dir ? bh1 : fh1, hall1,
                             bar + 128 + (dir ? 64 : 0), wg, dir, gl);
  }
}

// ---------------------------------------------------------------------------
// logits[r] = tanh(vh[r,:] + ws[b,:]) . atw + atw_b
// ---------------------------------------------------------------------------
__global__ __launch_bounds__(256) void logits_kernel(const float* __restrict__ vh,
                                                     const float* __restrict__ ws,
                                                     const float* __restrict__ atw,
                                                     const float* __restrict__ atwb,
                                                     float* __restrict__ lg)
{
  int wid  = (int)((blockIdx.x * 256 + threadIdx.x) >> 6);
  int lane = threadIdx.x & 63;
  if (wid >= 32768) return;
  int b = wid & 63;
  float x0 = vh[(size_t)wid * 128 + lane]      + ws[b * 128 + lane];
  float x1 = vh[(size_t)wid * 128 + 64 + lane] + ws[b * 128 + 64 + lane];
  float v = ftanh(x0) * atw[lane] + ftanh(x1) * atw[64 + lane];
  for (int off = 32; off; off >>= 1) v += __shfl_down(v, off);
  if (lane == 0) lg[wid] = v + atwb[0];
}

// ---------------------------------------------------------------------------
// Per-batch softmax over T + context
// ---------------------------------------------------------------------------
__global__ __launch_bounds__(256) void softmax_ctx(const float* __restrict__ lg,
                                                   const short* __restrict__ hall,
                                                   float* __restrict__ ctx, int C)
{
  int b = blockIdx.x, tid = threadIdx.x, lane = tid & 63, wv = tid >> 6;
  __shared__ float ebuf[512];
  __shared__ float red[8];
  float l0 = lg[tid * 64 + b];
  float l1 = lg[(tid + 256) * 64 + b];
  float m = fmaxf(l0, l1);
  for (int o = 32; o; o >>= 1) m = fmaxf(m, __shfl_xor(m, o));
  if (lane == 0) red[wv] = m;
  __syncthreads();
  m = fmaxf(fmaxf(red[0], red[1]), fmaxf(red[2], red[3]));
  float e0 = __expf(l0 - m), e1 = __expf(l1 - m);
  ebuf[tid] = e0; ebuf[tid + 256] = e1;
  float sm = e0 + e1;
  for (int o = 32; o; o >>= 1) sm += __shfl_xor(sm, o);
  if (lane == 0) red[4 + wv] = sm;
  __syncthreads();
  sm = red[4] + red[5] + red[6] + red[7];
  float inv = 1.f / (sm * 512.f);
  for (int c = tid; c < C; c += 256) {
    float acc = 0.f;
    const short* hp = hall + (size_t)b * C + c;
    for (int t = 0; t < 512; t++) acc += ebuf[t] * bf2f(hp[(size_t)t * 64 * C]);
    ctx[b * C + c] = acc * inv;
  }
}

// ---------------------------------------------------------------------------
__global__ __launch_bounds__(256) void final_kernel(const float* __restrict__ ctx0,
                                                    const float* __restrict__ ctx1,
                                                    const float* __restrict__ w0,
                                                    const float* __restrict__ b0,
                                                    const float* __restrict__ w1,
                                                    const float* __restrict__ b1,
                                                    float* __restrict__ out)
{
  int b = blockIdx.x, o = threadIdx.x;
  float acc = b0[o] + b1[o];
  for (int c = 0; c < 512; c++) acc += ctx0[b * 512 + c] * w0[c * 256 + o];
  for (int c = 0; c < 256; c++) acc += ctx1[b * 256 + c] * w1[c * 256 + o];
  out[b * 256 + o] = ftanh(acc);
}

// ---------------------------------------------------------------------------
extern "C" void kernel_launch(void* const* d_in, const int* in_sizes, int n_in,
                              void* d_out, int out_size, void* d_ws, size_t ws_size,
                              hipStream_t stream)
{
  const float* x0    = (const float*)d_in[0];
  const float* x1    = (const float*)d_in[1];
  const float* sIn   = (const float*)d_in[2];
  const float* emb_w0 = (const float*)d_in[3];  const float* emb_b0 = (const float*)d_in[4];
  const float* fx_w0  = (const float*)d_in[5];  const float* fx_b0  = (const float*)d_in[6];
  const float* fh_w0  = (const float*)d_in[7];
  const float* bx_w0  = (const float*)d_in[8];  const float* bx_b0  = (const float*)d_in[9];
  const float* bh_w0  = (const float*)d_in[10];
  const float* atV_w0 = (const float*)d_in[11]; const float* atV_b0 = (const float*)d_in[12];
  const float* atW_w0 = (const float*)d_in[13]; const float* atW_b0 = (const float*)d_in[14];
  const float* atw_w0 = (const float*)d_in[15]; const float* atw_b0 = (const float*)d_in[16];
  const float* lgd_w0 = (const float*)d_in[17]; const float* lgd_b0 = (const float*)d_in[18];
  const float* emb_w1 = (const float*)d_in[19]; const float* emb_b1 = (const float*)d_in[20];
  const float* fx_w1  = (const float*)d_in[21]; const float* fx_b1  = (const float*)d_in[22];
  const float* fh_w1  = (const float*)d_in[23];
  const float* bx_w1  = (const float*)d_in[24]; const float* bx_b1  = (const float*)d_in[25];
  const float* bh_w1  = (const float*)d_in[26];
  const float* atV_w1 = (const float*)d_in[27]; const float* atV_b1 = (const float*)d_in[28];
  const float* atW_w1 = (const float*)d_in[29]; const float* atW_b1 = (const float*)d_in[30];
  const float* atw_w1 = (const float*)d_in[31]; const float* atw_b1 = (const float*)d_in[32];
  const float* lgd_w1 = (const float*)d_in[33]; const float* lgd_b1 = (const float*)d_in[34];
  float* out = (float*)d_out;

  char* wp = (char*)d_ws;
  auto alloc = [&](size_t bytes) -> void* {
    void* p = wp; wp += (bytes + 255) & ~(size_t)255; return p;
  };
  int*   bar   = (int*)alloc(1024);
  short* h0_0  = (short*)alloc(32768ull * 512 * 2);
  short* h0_1  = (short*)alloc(32768ull * 128 * 2);
  short* xgf0  = (short*)alloc(32768ull * 1024 * 2);
  short* xgb0  = (short*)alloc(32768ull * 1024 * 2);
  short* xgf1  = (short*)alloc(32768ull * 512 * 2);
  short* xgb1  = (short*)alloc(32768ull * 512 * 2);
  short* hall0 = (short*)alloc(32768ull * 512 * 2);
  short* hall1 = (short*)alloc(32768ull * 256 * 2);
  float* vh0   = (float*)alloc(32768ull * 128 * 4);
  float* vh1   = (float*)alloc(32768ull * 128 * 4);
  float* wsb0  = (float*)alloc(64 * 128 * 4);
  float* wsb1  = (float*)alloc(64 * 128 * 4);
  float* lg0   = (float*)alloc(32768 * 4);
  float* lg1   = (float*)alloc(32768 * 4);
  float* ctx0  = (float*)alloc(64 * 512 * 4);
  float* ctx1  = (float*)alloc(64 * 256 * 4);
  // pre-transposed bf16 weights (Wt[N][K])
  short* emb_w0t = (short*)alloc(512ull  * 2048 * 2);
  short* fx_w0t  = (short*)alloc(1024ull * 512 * 2);
  short* bx_w0t  = (short*)alloc(1024ull * 512 * 2);
  short* emb_w1t = (short*)alloc(128ull  * 128 * 2);
  short* fx_w1t  = (short*)alloc(512ull  * 128 * 2);
  short* bx_w1t  = (short*)alloc(512ull  * 128 * 2);
  short* atV_w0t = (short*)alloc(128ull  * 512 * 2);
  short* atV_w1t = (short*)alloc(128ull  * 256 * 2);

  // weight preprocessing (transpose + bf16 cvt; rounding identical to before)
  transpose_cvt<<<dim3(64, 16), 256, 0, stream>>>(emb_w0, emb_w0t, 2048, 512);
  transpose_cvt<<<dim3(16, 32), 256, 0, stream>>>(fx_w0,  fx_w0t,  512, 1024);
  transpose_cvt<<<dim3(16, 32), 256, 0, stream>>>(bx_w0,  bx_w0t,  512, 1024);
  transpose_cvt<<<dim3(4, 4),   256, 0, stream>>>(emb_w1, emb_w1t, 128, 128);
  transpose_cvt<<<dim3(4, 16),  256, 0, stream>>>(fx_w1,  fx_w1t,  128, 512);
  transpose_cvt<<<dim3(4, 16),  256, 0, stream>>>(bx_w1,  bx_w1t,  128, 512);
  transpose_cvt<<<dim3(16, 4),  256, 0, stream>>>(atV_w0, atV_w0t, 512, 128);
  transpose_cvt<<<dim3(8, 4),   256, 0, stream>>>(atV_w1, atV_w1t, 256, 128);

  // embeddings (f32 A in, bf16 out)
  gemm_bias<1, 0><<<dim3(4, 256), 256, 0, stream>>>(x0, emb_w0t, emb_b0, h0_0, 32768, 512, 2048);
  gemm_bias<1, 0><<<dim3(1, 256), 256, 0, stream>>>(x1, emb_w1t, emb_b1, h0_1, 32768, 128, 128);
  // input projections (bf16 in, bf16 out)
  gemm_bias<0, 0><<<dim3(8, 256), 256, 0, stream>>>(h0_0, fx_w0t, fx_b0, xgf0, 32768, 1024, 512);
  gemm_bias<0, 0><<<dim3(8, 256), 256, 0, stream>>>(h0_0, bx_w0t, bx_b0, xgb0, 32768, 1024, 512);
  gemm_bias<0, 0><<<dim3(4, 256), 256, 0, stream>>>(h0_1, fx_w1t, fx_b1, xgf1, 32768, 512, 128);
  gemm_bias<0, 0><<<dim3(4, 256), 256, 0, stream>>>(h0_1, bx_w1t, bx_b1, xgb1, 32768, 512, 128);
  // attention s-projection
  att_ws_kernel<<<64, 128, 0, stream>>>(sIn, atW_w0, atW_b0, wsb0);
  att_ws_kernel<<<64, 128, 0, stream>>>(sIn, atW_w1, atW_b1, wsb1);

  // persistent bidirectional LSTM scans (one dispatch, 512 internal steps)
  hipMemsetAsync(bar, 0, 1024, stream);
  lstm_persistent<<<96, 256, 0, stream>>>(xgf0, xgb0, xgf1, xgb1,
                                          fh_w0, bh_w0, fh_w1, bh_w1,
                                          hall0, hall1, bar);

  // attention
  gemm_bias<0, 1><<<dim3(1, 256), 256, 0, stream>>>(hall0, atV_w0t, atV_b0, vh0, 32768, 128, 512);
  gemm_bias<0, 1><<<dim3(1, 256), 256, 0, stream>>>(hall1, atV_w1t, atV_b1, vh1, 32768, 128, 256);
  logits_kernel<<<8192, 256, 0, stream>>>(vh0, wsb0, atw_w0, atw_b0, lg0);
  logits_kernel<<<8192, 256, 0, stream>>>(vh1, wsb1, atw_w1, atw_b1, lg1);
  softmax_ctx<<<64, 256, 0, stream>>>(lg0, hall0, ctx0, 512);
  softmax_ctx<<<64, 256, 0, stream>>>(lg1, hall1, ctx1, 256);
  final_kernel<<<64, 256, 0, stream>>>(ctx0, ctx1, lgd_w0, lgd_b0, lgd_w1, lgd_b1, out);
}

// Round 16
// 2394.776 us; speedup vs baseline: 1.1800x; 1.0066x over previous
//
#include <hip/hip_runtime.h>

typedef __attribute__((ext_vector_type(4))) float  f32x4;
typedef __attribute__((ext_vector_type(8))) short  short8;
typedef __attribute__((ext_vector_type(4))) short  short4v;
typedef __attribute__((ext_vector_type(4))) int    int4v;

__device__ __forceinline__ float bf2f(short s){
  unsigned u = ((unsigned)(unsigned short)s) << 16;
  float f; __builtin_memcpy(&f, &u, 4); return f;
}
__device__ __forceinline__ short f2bf(float x){
  unsigned u; __builtin_memcpy(&u, &x, 4);
  u = (u + 0x7fffu + ((u >> 16) & 1u)) >> 16;
  return (short)u;
}
__device__ __forceinline__ float sigm(float x){ return 1.f / (1.f + __expf(-x)); }
__device__ __forceinline__ float ftanh(float x){ return 1.f - 2.f / (__expf(2.f * x) + 1.f); }

// ---- IC-coherent (sc1) pipelined vector ops: issue many, wait once ----
__device__ __forceinline__ short8 ld_b128_sc1(const short* p){
  short8 r;
  asm volatile("global_load_dwordx4 %0, %1, off sc1" : "=&v"(r) : "v"(p) : "memory");
  return r;
}
__device__ __forceinline__ int4v ld_i4_sc1(const int* p){
  int4v r;
  asm volatile("global_load_dwordx4 %0, %1, off sc1" : "=&v"(r) : "v"(p) : "memory");
  return r;
}
__device__ __forceinline__ void st_dword_sc1(int* p, int v){
  asm volatile("global_store_dword %0, %1, off sc1" :: "v"(p), "v"(v) : "memory");
}
__device__ __forceinline__ void wait_vm0(){
  asm volatile("s_waitcnt vmcnt(0)" ::: "memory");
  __builtin_amdgcn_sched_barrier(0);
}

// async global -> LDS, 16B per lane. LDS dest is WAVE-UNIFORM base; HW places
// lane l's 16B at base + l*16 (guide §5 / m97). Global src is per-lane.
__device__ __forceinline__ void gload16(const short* g, short* l){
  __builtin_amdgcn_global_load_lds(
      (const __attribute__((address_space(1))) void*)g,
      (__attribute__((address_space(3))) void*)l, 16, 0, 0);
}

// ---------------------------------------------------------------------------
// f32 -> bf16 bulk convert (grid-stride, vectorized)
// ---------------------------------------------------------------------------
__global__ __launch_bounds__(256) void cvt_f32_bf16(const float* __restrict__ in,
                                                    short* __restrict__ out, long n)
{
  long i = ((long)blockIdx.x * 256 + threadIdx.x) * 4;
  long stride = (long)gridDim.x * 1024;
  for (; i < n; i += stride) {
    f32x4 v = *(const f32x4*)(in + i);
    short4v o;
#pragma unroll
    for (int q = 0; q < 4; q++) o[q] = f2bf(v[q]);
    *(short4v*)(out + i) = o;
  }
}

// ---------------------------------------------------------------------------
// Merged weight transpose+cvt: Wt[n][k] = bf16(W[k][n]) for 8 matrices.
// ---------------------------------------------------------------------------
struct TD { const float* W; short* Wt; int K, N, b0, nb, nbx; };
struct TD8 { TD d[8]; };

__global__ __launch_bounds__(256) void transpose_all(TD8 ds)
{
  __shared__ float tile[32][33];
  int bx = blockIdx.x;
#pragma unroll
  for (int m = 0; m < 8; m++) {
    TD d = ds.d[m];
    if (bx >= d.b0 && bx < d.b0 + d.nb) {
      int lb = bx - d.b0;
      int kt = (lb % d.nbx) * 32, nt = (lb / d.nbx) * 32;
      int tx = threadIdx.x & 31, ty = threadIdx.x >> 5;
#pragma unroll
      for (int i = 0; i < 4; i++) {
        int k = kt + ty + i * 8, n = nt + tx;
        if (k < d.K && n < d.N) tile[ty + i * 8][tx] = d.W[(size_t)k * d.N + n];
      }
      __syncthreads();
#pragma unroll
      for (int i = 0; i < 4; i++) {
        int n = nt + ty + i * 8, k = kt + tx;
        if (n < d.N && k < d.K) d.Wt[(size_t)n * d.K + k] = f2bf(tile[tx][ty + i * 8]);
      }
      return;
    }
  }
}

// ---------------------------------------------------------------------------
// Unified bf16 MFMA GEMM, m97-style staging:
//   C[M,N] = A[M,K](bf16) * Bt[N,K](bf16)^T + bias
//   As/Bs are LINEAR [128][32] (64B rows); staged via global_load_lds 16B/lane
//   (wave w stages rows [w*32, w*32+32) of each tile with 2 instrs).
// OF32: 1 -> f32 C, 0 -> bf16 C.
// ---------------------------------------------------------------------------
__global__ __launch_bounds__(256) void gemm_bt(const short* __restrict__ A,
                                               const short* __restrict__ Bt,
                                               const float* __restrict__ bias,
                                               void* __restrict__ Cv,
                                               int M, int N, int K, int OF32)
{
  __shared__ __align__(16) short As[128 * 32];
  __shared__ __align__(16) short Bs[128 * 32];
  int tid  = threadIdx.x;
  int col0 = blockIdx.x * 128, row0 = blockIdx.y * 128;
  int lane = tid & 63, w = tid >> 6;
  int wm = (w >> 1) * 64, wn = (w & 1) * 64;
  int lr = lane >> 2, lc = (lane & 3) * 8;     // lane's (row, col8) in a 16-row chunk

  f32x4 acc[4][4];
  for (int mi = 0; mi < 4; mi++)
    for (int ni = 0; ni < 4; ni++)
      for (int q = 0; q < 4; q++) acc[mi][ni][q] = 0.f;

  for (int kt = 0; kt < K; kt += 32) {
    __syncthreads();
#pragma unroll
    for (int i = 0; i < 2; i++) {
      int rbase = w * 32 + i * 16;
      gload16(A  + (size_t)(row0 + rbase + lr) * K + kt + lc, &As[rbase * 32]);
      gload16(Bt + (size_t)(col0 + rbase + lr) * K + kt + lc, &Bs[rbase * 32]);
    }
    __syncthreads();   // drains vmcnt (incl. global_load_lds)

    int fr = lane & 15, fo = (lane >> 4) << 3;
    short8 af[4], bfr[4];
    for (int mi = 0; mi < 4; mi++) af[mi]  = *(short8*)&As[(wm + mi * 16 + fr) * 32 + fo];
    for (int ni = 0; ni < 4; ni++) bfr[ni] = *(short8*)&Bs[(wn + ni * 16 + fr) * 32 + fo];
    for (int mi = 0; mi < 4; mi++)
      for (int ni = 0; ni < 4; ni++)
        acc[mi][ni] = __builtin_amdgcn_mfma_f32_16x16x32_bf16(af[mi], bfr[ni], acc[mi][ni], 0, 0, 0);
  }

  int efr = lane & 15, efrow = (lane >> 4) << 2;
  for (int ni = 0; ni < 4; ni++) {
    int col = col0 + wn + ni * 16 + efr;
    float bv = bias[col];
    for (int mi = 0; mi < 4; mi++) {
      for (int q = 0; q < 4; q++) {
        int row = row0 + wm + mi * 16 + efrow + q;
        float v = acc[mi][ni][q] + bv;
        if (OF32) ((float*)Cv)[(size_t)row * N + col] = v;
        else      ((short*)Cv)[(size_t)row * N + col] = f2bf(v);
      }
    }
  }
}

// ---------------------------------------------------------------------------
// ws = s @ atW + atW_b
// ---------------------------------------------------------------------------
__global__ __launch_bounds__(128) void att_ws_kernel(const float* __restrict__ s,
                                                     const float* __restrict__ atW,
                                                     const float* __restrict__ atWb,
                                                     float* __restrict__ ws)
{
  int b = blockIdx.x, a = threadIdx.x;
  float acc = atWb[a];
  for (int k = 0; k < 128; k++) acc += s[b * 128 + k] * atW[k * 128 + a];
  ws[b * 128 + a] = acc;
}

// ---------------------------------------------------------------------------
// Persistent bidirectional-LSTM scan — R10 structure (verified 1757-1775us):
//   (a) h_prev loads: pipelined b128 sc1 loads, ONE vmcnt wait, then MFMAs
//   (b) step barrier: per-block flag store + tid0 pipelined flag poll
// ---------------------------------------------------------------------------
template<int H, int NB>
__device__ __forceinline__ void persistent_scan(
    const short* __restrict__ xg, const float* __restrict__ Wh,
    short* __restrict__ hall, int* __restrict__ flags,
    int wg, int dir, float* gl)
{
  constexpr int C = 2 * H, H4 = 4 * H, KB = H / 32;
  int tid = threadIdx.x, lane = tid & 63, w = tid >> 6;
  int j0 = wg * 8, dircol = dir ? H : 0;
  int n = lane & 15, ko = (lane >> 4) << 3;

  short8 bw[2][KB];
#pragma unroll
  for (int nt = 0; nt < 2; nt++) {
    int col = (n >> 2) * H + j0 + nt * 4 + (n & 3);
#pragma unroll
    for (int kb = 0; kb < KB; kb++)
#pragma unroll
      for (int e = 0; e < 8; e++)
        bw[nt][kb][e] = f2bf(Wh[(size_t)(kb * 32 + ko + e) * H4 + col]);
  }

  int batch0 = w * 16 + ((lane >> 4) << 2);
  int rowA   = w * 16 + n;
  int eb = tid >> 2, ejp = tid & 3;
  float c0 = 0.f, c1 = 0.f;

  int t = dir ? 511 : 0;
  short xgr[2][4];
#pragma unroll
  for (int nt = 0; nt < 2; nt++) {
    int col = (n >> 2) * H + j0 + nt * 4 + (n & 3);
#pragma unroll
    for (int q = 0; q < 4; q++)
      xgr[nt][q] = xg[(size_t)(t * 64 + batch0 + q) * H4 + col];
  }

  for (int s = 0; s < 512; s++) {
    t = dir ? 511 - s : s;
    f32x4 acc[2];
#pragma unroll
    for (int q = 0; q < 4; q++) { acc[0][q] = 0.f; acc[1][q] = 0.f; }

    if (s > 0) {
      int tprev = dir ? t + 1 : t - 1;
      const short* hb = hall + ((size_t)tprev * 64 + rowA) * C + dircol;
      short8 hv[KB];
#pragma unroll
      for (int kb = 0; kb < KB; kb++)
        hv[kb] = ld_b128_sc1(hb + kb * 32 + ko);
      wait_vm0();
#pragma unroll
      for (int kb = 0; kb < KB; kb++) {
        acc[0] = __builtin_amdgcn_mfma_f32_16x16x32_bf16(hv[kb], bw[0][kb], acc[0], 0, 0, 0);
        acc[1] = __builtin_amdgcn_mfma_f32_16x16x32_bf16(hv[kb], bw[1][kb], acc[1], 0, 0, 0);
      }
    }

#pragma unroll
    for (int nt = 0; nt < 2; nt++) {
      int gcol = (n >> 2) * 8 + nt * 4 + (n & 3);
#pragma unroll
      for (int q = 0; q < 4; q++)
        gl[(batch0 + q) * 33 + gcol] = acc[nt][q] + bf2f(xgr[nt][q]);
    }
    __syncthreads();

    {
      const float* gb = gl + eb * 33 + ejp * 2;
      float a0 = gb[0],  a1 = gb[1];
      float i0 = gb[8],  i1 = gb[9];
      float f0 = gb[16], f1 = gb[17];
      float o0 = gb[24], o1 = gb[25];
      c0 = ftanh(a0) * sigm(i0) + c0 * sigm(f0);
      c1 = ftanh(a1) * sigm(i1) + c1 * sigm(f1);
      unsigned h0 = (unsigned short)f2bf(ftanh(c0) * sigm(o0));
      unsigned h1 = (unsigned short)f2bf(ftanh(c1) * sigm(o1));
      st_dword_sc1((int*)(hall + ((size_t)t * 64 + eb) * C + dircol + j0 + ejp * 2),
                   (int)(h0 | (h1 << 16)));
    }

    if (s < 511) {
      wait_vm0();
      __syncthreads();
      if (tid == 0) st_dword_sc1(flags + wg, s + 1);

      int tn = dir ? t - 1 : t + 1;
#pragma unroll
      for (int nt = 0; nt < 2; nt++) {
        int col = (n >> 2) * H + j0 + nt * 4 + (n & 3);
#pragma unroll
        for (int q = 0; q < 4; q++)
          xgr[nt][q] = xg[(size_t)(tn * 64 + batch0 + q) * H4 + col];
      }

      if (tid == 0) {
        for (;;) {
          int4v f[NB / 4];
#pragma unroll
          for (int i = 0; i < NB / 4; i++) f[i] = ld_i4_sc1(flags + i * 4);
          wait_vm0();
          int ok = 1;
#pragma unroll
          for (int i = 0; i < NB / 4; i++)
#pragma unroll
            for (int j = 0; j < 4; j++) ok &= (f[i][j] > s);
          if (ok) break;
          __builtin_amdgcn_s_sleep(1);
        }
      }
      __syncthreads();
    }
  }
}

__global__ __launch_bounds__(256) void lstm_persistent(
    const short* __restrict__ xgf0, const short* __restrict__ xgb0,
    const short* __restrict__ xgf1, const short* __restrict__ xgb1,
    const float* __restrict__ fh0, const float* __restrict__ bh0,
    const float* __restrict__ fh1, const float* __restrict__ bh1,
    short* __restrict__ hall0, short* __restrict__ hall1, int* __restrict__ bar)
{
  __shared__ float gl[64 * 33];
  int bx = blockIdx.x;
  if (bx < 64) {
    int dir = bx >> 5, wg = bx & 31;
    persistent_scan<256, 32>(dir ? xgb0 : xgf0, dir ? bh0 : fh0, hall0,
                             bar + (dir ? 64 : 0), wg, dir, gl);
  } else {
    int r = bx - 64, dir = r >> 4, wg = r & 15;
    persistent_scan<128, 16>(dir ? xgb1 : xgf1, dir ? bh1 : fh1, hall1,
                             bar + 128 + (dir ? 64 : 0), wg, dir, gl);
  }
}

// ---------------------------------------------------------------------------
// logits[r] = tanh(vh[r,:] + ws[b,:]) . atw + atw_b
// ---------------------------------------------------------------------------
__global__ __launch_bounds__(256) void logits_kernel(const float* __restrict__ vh,
                                                     const float* __restrict__ ws,
                                                     const float* __restrict__ atw,
                                                     const float* __restrict__ atwb,
                                                     float* __restrict__ lg)
{
  int wid  = (int)((blockIdx.x * 256 + threadIdx.x) >> 6);
  int lane = threadIdx.x & 63;
  if (wid >= 32768) return;
  int b = wid & 63;
  float x0 = vh[(size_t)wid * 128 + lane]      + ws[b * 128 + lane];
  float x1 = vh[(size_t)wid * 128 + 64 + lane] + ws[b * 128 + 64 + lane];
  float v = ftanh(x0) * atw[lane] + ftanh(x1) * atw[64 + lane];
  for (int off = 32; off; off >>= 1) v += __shfl_down(v, off);
  if (lane == 0) lg[wid] = v + atwb[0];
}

// ---------------------------------------------------------------------------
// Per-batch softmax over T + context
// ---------------------------------------------------------------------------
__global__ __launch_bounds__(256) void softmax_ctx(const float* __restrict__ lg,
                                                   const short* __restrict__ hall,
                                                   float* __restrict__ ctx, int C)
{
  int b = blockIdx.x, tid = threadIdx.x, lane = tid & 63, wv = tid >> 6;
  __shared__ float ebuf[512];
  __shared__ float red[8];
  float l0 = lg[tid * 64 + b];
  float l1 = lg[(tid + 256) * 64 + b];
  float m = fmaxf(l0, l1);
  for (int o = 32; o; o >>= 1) m = fmaxf(m, __shfl_xor(m, o));
  if (lane == 0) red[wv] = m;
  __syncthreads();
  m = fmaxf(fmaxf(red[0], red[1]), fmaxf(red[2], red[3]));
  float e0 = __expf(l0 - m), e1 = __expf(l1 - m);
  ebuf[tid] = e0; ebuf[tid + 256] = e1;
  float sm = e0 + e1;
  for (int o = 32; o; o >>= 1) sm += __shfl_xor(sm, o);
  if (lane == 0) red[4 + wv] = sm;
  __syncthreads();
  sm = red[4] + red[5] + red[6] + red[7];
  float inv = 1.f / (sm * 512.f);
  for (int c = tid; c < C; c += 256) {
    float acc = 0.f;
    const short* hp = hall + (size_t)b * C + c;
    for (int t = 0; t < 512; t++) acc += ebuf[t] * bf2f(hp[(size_t)t * 64 * C]);
    ctx[b * C + c] = acc * inv;
  }
}

// ---------------------------------------------------------------------------
__global__ __launch_bounds__(256) void final_kernel(const float* __restrict__ ctx0,
                                                    const float* __restrict__ ctx1,
                                                    const float* __restrict__ w0,
                                                    const float* __restrict__ b0,
                                                    const float* __restrict__ w1,
                                                    const float* __restrict__ b1,
                                                    float* __restrict__ out)
{
  int b = blockIdx.x, o = threadIdx.x;
  float acc = b0[o] + b1[o];
  for (int c = 0; c < 512; c++) acc += ctx0[b * 512 + c] * w0[c * 256 + o];
  for (int c = 0; c < 256; c++) acc += ctx1[b * 256 + c] * w1[c * 256 + o];
  out[b * 256 + o] = ftanh(acc);
}

// ---------------------------------------------------------------------------
extern "C" void kernel_launch(void* const* d_in, const int* in_sizes, int n_in,
                              void* d_out, int out_size, void* d_ws, size_t ws_size,
                              hipStream_t stream)
{
  const float* x0    = (const float*)d_in[0];
  const float* x1    = (const float*)d_in[1];
  const float* sIn   = (const float*)d_in[2];
  const float* emb_w0 = (const float*)d_in[3];  const float* emb_b0 = (const float*)d_in[4];
  const float* fx_w0  = (const float*)d_in[5];  const float* fx_b0  = (const float*)d_in[6];
  const float* fh_w0  = (const float*)d_in[7];
  const float* bx_w0  = (const float*)d_in[8];  const float* bx_b0  = (const float*)d_in[9];
  const float* bh_w0  = (const float*)d_in[10];
  const float* atV_w0 = (const float*)d_in[11]; const float* atV_b0 = (const float*)d_in[12];
  const float* atW_w0 = (const float*)d_in[13]; const float* atW_b0 = (const float*)d_in[14];
  const float* atw_w0 = (const float*)d_in[15]; const float* atw_b0 = (const float*)d_in[16];
  const float* lgd_w0 = (const float*)d_in[17]; const float* lgd_b0 = (const float*)d_in[18];
  const float* emb_w1 = (const float*)d_in[19]; const float* emb_b1 = (const float*)d_in[20];
  const float* fx_w1  = (const float*)d_in[21]; const float* fx_b1  = (const float*)d_in[22];
  const float* fh_w1  = (const float*)d_in[23];
  const float* bx_w1  = (const float*)d_in[24]; const float* bx_b1  = (const float*)d_in[25];
  const float* bh_w1  = (const float*)d_in[26];
  const float* atV_w1 = (const float*)d_in[27]; const float* atV_b1 = (const float*)d_in[28];
  const float* atW_w1 = (const float*)d_in[29]; const float* atW_b1 = (const float*)d_in[30];
  const float* atw_w1 = (const float*)d_in[31]; const float* atw_b1 = (const float*)d_in[32];
  const float* lgd_w1 = (const float*)d_in[33]; const float* lgd_b1 = (const float*)d_in[34];
  float* out = (float*)d_out;

  char* wp = (char*)d_ws;
  auto alloc = [&](size_t bytes) -> void* {
    void* p = wp; wp += (bytes + 255) & ~(size_t)255; return p;
  };
  int*   bar   = (int*)alloc(1024);
  short* h0_0  = (short*)alloc(32768ull * 512 * 2);
  short* h0_1  = (short*)alloc(32768ull * 128 * 2);
  short* xgf0  = (short*)alloc(32768ull * 1024 * 2);   // also hosts x0b pre-cvt
  short* xgb0  = (short*)alloc(32768ull * 1024 * 2);   // (x0b spans xgf0+xgb0)
  short* xgf1  = (short*)alloc(32768ull * 512 * 2);    // also hosts x1b pre-cvt
  short* xgb1  = (short*)alloc(32768ull * 512 * 2);
  short* hall0 = (short*)alloc(32768ull * 512 * 2);
  short* hall1 = (short*)alloc(32768ull * 256 * 2);
  float* vh0   = (float*)alloc(32768ull * 128 * 4);
  float* vh1   = (float*)alloc(32768ull * 128 * 4);
  float* wsb0  = (float*)alloc(64 * 128 * 4);
  float* wsb1  = (float*)alloc(64 * 128 * 4);
  float* lg0   = (float*)alloc(32768 * 4);
  float* lg1   = (float*)alloc(32768 * 4);
  float* ctx0  = (float*)alloc(64 * 512 * 4);
  float* ctx1  = (float*)alloc(64 * 256 * 4);
  short* emb_w0t = (short*)alloc(512ull  * 2048 * 2);
  short* fx_w0t  = (short*)alloc(1024ull * 512 * 2);
  short* bx_w0t  = (short*)alloc(1024ull * 512 * 2);
  short* emb_w1t = (short*)alloc(128ull  * 128 * 2);
  short* fx_w1t  = (short*)alloc(512ull  * 128 * 2);
  short* bx_w1t  = (short*)alloc(512ull  * 128 * 2);
  short* atV_w0t = (short*)alloc(128ull  * 512 * 2);
  short* atV_w1t = (short*)alloc(128ull  * 256 * 2);
  short* x0b = xgf0;            // 134.2MB = xgf0+xgb0; dead before fx0/bx0 write
  short* x1b = xgf1;            // 8.4MB subset of xgf1; dead before fx1 writes

  // input pre-convert (rounding identical to the old in-GEMM cvt)
  cvt_f32_bf16<<<2048, 256, 0, stream>>>(x0, x0b, 32768ll * 2048);
  cvt_f32_bf16<<<512,  256, 0, stream>>>(x1, x1b, 32768ll * 128);

  // merged weight transpose+cvt (8 matrices, one launch)
  {
    TD8 ds; int b0 = 0;
    auto set = [&](int i, const float* W, short* Wt, int K, int N){
      int nbx = (K + 31) / 32, nby = (N + 31) / 32;
      ds.d[i] = TD{W, Wt, K, N, b0, nbx * nby, nbx};
      b0 += nbx * nby;
    };
    set(0, emb_w0, emb_w0t, 2048, 512);
    set(1, fx_w0,  fx_w0t,  512, 1024);
    set(2, bx_w0,  bx_w0t,  512, 1024);
    set(3, emb_w1, emb_w1t, 128, 128);
    set(4, fx_w1,  fx_w1t,  128, 512);
    set(5, bx_w1,  bx_w1t,  128, 512);
    set(6, atV_w0, atV_w0t, 512, 128);
    set(7, atV_w1, atV_w1t, 256, 128);
    transpose_all<<<b0, 256, 0, stream>>>(ds);
  }

  // embeddings
  gemm_bt<<<dim3(4, 256), 256, 0, stream>>>(x0b, emb_w0t, emb_b0, h0_0, 32768, 512, 2048, 0);
  gemm_bt<<<dim3(1, 256), 256, 0, stream>>>(x1b, emb_w1t, emb_b1, h0_1, 32768, 128, 128, 0);
  // input projections (xgf0 write overwrites x0b region — x0b already consumed)
  gemm_bt<<<dim3(8, 256), 256, 0, stream>>>(h0_0, fx_w0t, fx_b0, xgf0, 32768, 1024, 512, 0);
  gemm_bt<<<dim3(8, 256), 256, 0, stream>>>(h0_0, bx_w0t, bx_b0, xgb0, 32768, 1024, 512, 0);
  gemm_bt<<<dim3(4, 256), 256, 0, stream>>>(h0_1, fx_w1t, fx_b1, xgf1, 32768, 512, 128, 0);
  gemm_bt<<<dim3(4, 256), 256, 0, stream>>>(h0_1, bx_w1t, bx_b1, xgb1, 32768, 512, 128, 0);
  // attention s-projection
  att_ws_kernel<<<64, 128, 0, stream>>>(sIn, atW_w0, atW_b0, wsb0);
  att_ws_kernel<<<64, 128, 0, stream>>>(sIn, atW_w1, atW_b1, wsb1);

  // persistent bidirectional LSTM scans
  hipMemsetAsync(bar, 0, 1024, stream);
  lstm_persistent<<<96, 256, 0, stream>>>(xgf0, xgb0, xgf1, xgb1,
                                          fh_w0, bh_w0, fh_w1, bh_w1,
                                          hall0, hall1, bar);

  // attention
  gemm_bt<<<dim3(1, 256), 256, 0, stream>>>(hall0, atV_w0t, atV_b0, vh0, 32768, 128, 512, 1);
  gemm_bt<<<dim3(1, 256), 256, 0, stream>>>(hall1, atV_w1t, atV_b1, vh1, 32768, 128, 256, 1);
  logits_kernel<<<8192, 256, 0, stream>>>(vh0, wsb0, atw_w0, atw_b0, lg0);
  logits_kernel<<<8192, 256, 0, stream>>>(vh1, wsb1, atw_w1, atw_b1, lg1);
  softmax_ctx<<<64, 256, 0, stream>>>(lg0, hall0, ctx0, 512);
  softmax_ctx<<<64, 256, 0, stream>>>(lg1, hall1, ctx1, 256);
  final_kernel<<<64, 256, 0, stream>>>(ctx0, ctx1, lgd_w0, lgd_b0, lgd_w1, lgd_b1, out);
}